// Round 1
// baseline (8803.218 us; speedup 1.0000x reference)
//
#include <hip/hip_runtime.h>
#include <hip/hip_bf16.h>

// Problem constants
#define T_STEPS 64
#define BATCH   32
#define HID     1024
#define VOCAB   32000
#define WLEN_   101
#define WSZ_    50
#define SENC    229

static const size_t Y_SZ   = (size_t)T_STEPS * BATCH * VOCAB;   // 65,536,000
static const size_t HN_SZ  = (size_t)2 * BATCH * HID;           // 65,536
static const size_t CTX_OFF = Y_SZ + 2 * HN_SZ;                 // y + h_n + c_n

// ---------------------------------------------------------------------------
// Generic fp32 GEMM: out[M,N] = A[M,K] @ W[N,K]^T + b1 + b2, optional act.
// Tile 128x64, K-step 16, 256 threads, 8x4 per-thread microtile.
// Requires M%128==0, N%64==0, K%16==0 (true for all call sites).
// act: 0 none, 1 relu, 2 tanh
// ---------------------------------------------------------------------------
__global__ __launch_bounds__(256) void gemm_bt(
    const float* __restrict__ A, const float* __restrict__ W,
    const float* __restrict__ b1, const float* __restrict__ b2,
    float* __restrict__ out, int M, int N, int K, int act)
{
    __shared__ __align__(16) float As[16 * 132];   // transposed [k][r], pad 132
    __shared__ __align__(16) float Ws[16 * 68];    // transposed [k][n], pad 68
    const int tid  = threadIdx.x;
    const int col0 = blockIdx.x * 64;
    const int row0 = blockIdx.y * 128;
    const int ty   = tid >> 4;   // 0..15
    const int tx   = tid & 15;   // 0..15

    float acc[8][4];
#pragma unroll
    for (int i = 0; i < 8; ++i)
#pragma unroll
        for (int j = 0; j < 4; ++j) acc[i][j] = 0.f;

    for (int k0 = 0; k0 < K; k0 += 16) {
#pragma unroll
        for (int li = 0; li < 2; ++li) {
            int f  = tid + li * 256;
            int r  = f >> 2;
            int kq = (f & 3) << 2;
            float4 v = *reinterpret_cast<const float4*>(A + (size_t)(row0 + r) * K + k0 + kq);
            As[(kq + 0) * 132 + r] = v.x;
            As[(kq + 1) * 132 + r] = v.y;
            As[(kq + 2) * 132 + r] = v.z;
            As[(kq + 3) * 132 + r] = v.w;
        }
        {
            int n  = tid >> 2;
            int kq = (tid & 3) << 2;
            float4 v = *reinterpret_cast<const float4*>(W + (size_t)(col0 + n) * K + k0 + kq);
            Ws[(kq + 0) * 68 + n] = v.x;
            Ws[(kq + 1) * 68 + n] = v.y;
            Ws[(kq + 2) * 68 + n] = v.z;
            Ws[(kq + 3) * 68 + n] = v.w;
        }
        __syncthreads();
#pragma unroll
        for (int k = 0; k < 16; ++k) {
            const float4 a0 = *reinterpret_cast<const float4*>(&As[k * 132 + ty * 8]);
            const float4 a1 = *reinterpret_cast<const float4*>(&As[k * 132 + ty * 8 + 4]);
            const float4 b0 = *reinterpret_cast<const float4*>(&Ws[k * 68 + tx * 4]);
            float av[8] = {a0.x, a0.y, a0.z, a0.w, a1.x, a1.y, a1.z, a1.w};
            float bv[4] = {b0.x, b0.y, b0.z, b0.w};
#pragma unroll
            for (int i = 0; i < 8; ++i)
#pragma unroll
                for (int j = 0; j < 4; ++j) acc[i][j] = fmaf(av[i], bv[j], acc[i][j]);
        }
        __syncthreads();
    }

#pragma unroll
    for (int j = 0; j < 4; ++j) {
        int n = col0 + tx * 4 + j;
        float bias = 0.f;
        if (b1) bias += b1[n];
        if (b2) bias += b2[n];
#pragma unroll
        for (int i = 0; i < 8; ++i) {
            float v = acc[i][j] + bias;
            if (act == 1) v = fmaxf(v, 0.f);
            else if (act == 2) v = tanhf(v);
            out[(size_t)(row0 + ty * 8 + i) * N + n] = v;
        }
    }
}

// ---------------------------------------------------------------------------
// Embedding lookup + input-feeding concat: x[t*B+b, 0:H]=emb[tw], [H:2H]=context
// ---------------------------------------------------------------------------
__global__ void embed_concat_kernel(const float* __restrict__ emb,
                                    const float* __restrict__ ctxin,
                                    const int* __restrict__ tw,
                                    float* __restrict__ x)
{
    const size_t total = (size_t)2048 * 2048;
    for (size_t idx = (size_t)blockIdx.x * blockDim.x + threadIdx.x; idx < total;
         idx += (size_t)gridDim.x * blockDim.x) {
        int h = (int)(idx & 2047);
        size_t row = idx >> 11;
        float v;
        if (h < HID) v = emb[(size_t)tw[row] * HID + h];
        else         v = ctxin[row * HID + (h - HID)];
        x[idx] = v;
    }
}

// ---------------------------------------------------------------------------
// One LSTM step: gates = gpre + h_in @ Whh^T, then elementwise update.
// grid 256 blocks x 128 threads; thread owns (b = tid&31, j = blk*4 + tid>>5).
// h chunk staged in LDS with stride 260 (bank-conflict-free across b).
// ---------------------------------------------------------------------------
__global__ __launch_bounds__(128) void lstm_step_kernel(
    const float* __restrict__ gpre,   // [32,4096] slice at t
    const float* __restrict__ Whh,    // [4096,1024]
    const float* __restrict__ h_in,   // [32,1024]
    float* __restrict__ c_io,         // [32,1024] in-place
    float* __restrict__ h_out,        // [32,1024]
    float* __restrict__ y_out)        // [32,1024] slice of layer output at t
{
    __shared__ __align__(16) float hs[32 * 260];
    const int tid = threadIdx.x;
    const int b  = tid & 31;
    const int jl = tid >> 5;                 // 0..3
    const int j  = blockIdx.x * 4 + jl;      // 0..1023
    const float* w0 = Whh + (size_t)j * HID;
    const float* w1 = Whh + (size_t)(HID + j) * HID;
    const float* w2 = Whh + (size_t)(2 * HID + j) * HID;
    const float* w3 = Whh + (size_t)(3 * HID + j) * HID;
    float a0 = 0.f, a1 = 0.f, a2 = 0.f, a3 = 0.f;

    for (int kk = 0; kk < HID; kk += 256) {
        for (int f = tid; f < 2048; f += 128) {        // 32 rows x 64 float4
            int bb = f >> 6;
            int k4 = f & 63;
            float4 v = *reinterpret_cast<const float4*>(h_in + (size_t)bb * HID + kk + k4 * 4);
            *reinterpret_cast<float4*>(&hs[bb * 260 + k4 * 4]) = v;
        }
        __syncthreads();
        const float4* hv = reinterpret_cast<const float4*>(&hs[b * 260]);
#pragma unroll 4
        for (int q = 0; q < 64; ++q) {
            float4 h4 = hv[q];
            float4 x0 = *reinterpret_cast<const float4*>(w0 + kk + q * 4);
            float4 x1 = *reinterpret_cast<const float4*>(w1 + kk + q * 4);
            float4 x2 = *reinterpret_cast<const float4*>(w2 + kk + q * 4);
            float4 x3 = *reinterpret_cast<const float4*>(w3 + kk + q * 4);
            a0 += h4.x * x0.x + h4.y * x0.y + h4.z * x0.z + h4.w * x0.w;
            a1 += h4.x * x1.x + h4.y * x1.y + h4.z * x1.z + h4.w * x1.w;
            a2 += h4.x * x2.x + h4.y * x2.y + h4.z * x2.z + h4.w * x2.w;
            a3 += h4.x * x3.x + h4.y * x3.y + h4.z * x3.z + h4.w * x3.w;
        }
        __syncthreads();
    }

    const int bi = b * 4096;
    float pi = gpre[bi + j]            + a0;   // gate order: i, f, g, o
    float pf = gpre[bi + HID + j]      + a1;
    float pg = gpre[bi + 2 * HID + j]  + a2;
    float po = gpre[bi + 3 * HID + j]  + a3;
    float ig = 1.f / (1.f + expf(-pi));
    float fg = 1.f / (1.f + expf(-pf));
    float gg = tanhf(pg);
    float og = 1.f / (1.f + expf(-po));
    float c  = fg * c_io[b * HID + j] + ig * gg;
    c_io[b * HID + j] = c;
    float h  = og * tanhf(c);
    h_out[b * HID + j] = h;
    y_out[b * HID + j] = h;
}

// ---------------------------------------------------------------------------
// Attention p: p_sig = sigmoid(hidden1 @ aw2 + ab2); p = 50 + len*p_sig;
// win = rint(len * p_sig). One 64-lane wave per (t,b) row.
// ---------------------------------------------------------------------------
__global__ __launch_bounds__(64) void attn_p_kernel(
    const float* __restrict__ hidden1, const float* __restrict__ aw2,
    const float* __restrict__ ab2, const int* __restrict__ lengths,
    float* __restrict__ p_arr, int* __restrict__ win_arr)
{
    const int row = blockIdx.x;        // t*B + b
    const int lane = threadIdx.x;
    float s = 0.f;
    for (int i = lane; i < 512; i += 64) s += hidden1[(size_t)row * 512 + i] * aw2[i];
    for (int off = 32; off > 0; off >>= 1) s += __shfl_down(s, off);
    if (lane == 0) {
        float v = s + ab2[0];
        float sig = 1.f / (1.f + expf(-v));
        int b = row & 31;
        float lf = (float)lengths[b];
        p_arr[row] = (float)WSZ_ + lf * sig;
        win_arr[row] = (int)rintf(lf * sig);   // round(p - WSZ), half-to-even
    }
}

// ---------------------------------------------------------------------------
// Selection gather (uses LAST decoder step's window, per reference):
// sel[b][w][h] = enc[win_last[b]+w][b][h]
// ---------------------------------------------------------------------------
__global__ void sel_gather_kernel(const float* __restrict__ enc,
                                  const int* __restrict__ win_arr,
                                  float* __restrict__ sel)
{
    const int total = BATCH * WLEN_ * HID;
    for (int idx = blockIdx.x * blockDim.x + threadIdx.x; idx < total;
         idx += gridDim.x * blockDim.x) {
        int h = idx & 1023;
        int w = (idx >> 10) % WLEN_;
        int b = idx / (WLEN_ * HID);
        int s = win_arr[(T_STEPS - 1) * BATCH + b] + w;
        sel[idx] = enc[((size_t)s * BATCH + b) * HID + h];
    }
}

// ---------------------------------------------------------------------------
// Fused attention per (t,b) row: score -> mask(EPS) -> softmax -> *gaussian -> ctx
// ---------------------------------------------------------------------------
__global__ __launch_bounds__(128) void attn_fused_kernel(
    const float* __restrict__ y1, const float* __restrict__ sel,
    const float* __restrict__ p_arr, const int* __restrict__ win_arr,
    const int* __restrict__ lengths, float* __restrict__ ctx)
{
    __shared__ __align__(16) float yl[1024];
    __shared__ float sv[WLEN_];
    __shared__ float av[WLEN_];
    const int row = blockIdx.x;     // t*B + b
    const int b   = row & 31;
    const int tid = threadIdx.x;

    for (int i = tid; i < 1024; i += 128) yl[i] = y1[(size_t)row * HID + i];
    __syncthreads();

    const int win = win_arr[row];
    const float p = p_arr[row];
    const int len = lengths[b];

    if (tid < WLEN_) {
        const float4* s4 = reinterpret_cast<const float4*>(sel + ((size_t)b * WLEN_ + tid) * HID);
        const float4* y4 = reinterpret_cast<const float4*>(yl);
        float acc = 0.f;
        for (int q = 0; q < 256; ++q) {
            float4 a = s4[q]; float4 yy = y4[q];
            acc += a.x * yy.x + a.y * yy.y + a.z * yy.z + a.w * yy.w;
        }
        bool lo = tid < (WSZ_ - win);
        bool hi = tid >= (len + WSZ_ - win);
        sv[tid] = (lo || hi) ? 1e-14f : acc;
    }
    __syncthreads();

    float mx = -1e30f;
    for (int w = 0; w < WLEN_; ++w) mx = fmaxf(mx, sv[w]);
    float sum = 0.f;
    for (int w = 0; w < WLEN_; ++w) sum += expf(sv[w] - mx);
    if (tid < WLEN_) {
        float e = expf(sv[tid] - mx) / sum;
        float d = (float)(win + tid) - p;
        av[tid] = e * expf(-(d * d) / 1250.f);   // 2*STD2 = 1250
    }
    __syncthreads();

    float acc[8] = {0, 0, 0, 0, 0, 0, 0, 0};
    for (int w = 0; w < WLEN_; ++w) {
        float a = av[w];
        const float* srow = sel + ((size_t)b * WLEN_ + w) * HID;
#pragma unroll
        for (int i = 0; i < 8; ++i) acc[i] += a * srow[tid + 128 * i];
    }
    for (int i = 0; i < 8; ++i) ctx[(size_t)row * HID + tid + 128 * i] = acc[i];
}

// ---------------------------------------------------------------------------
// Concat [ctx, y1] -> fin [2048, 2048]
// ---------------------------------------------------------------------------
__global__ void concat_fin_kernel(const float* __restrict__ ctx,
                                  const float* __restrict__ y1,
                                  float* __restrict__ fin)
{
    const size_t total = (size_t)2048 * 2048;
    for (size_t idx = (size_t)blockIdx.x * blockDim.x + threadIdx.x; idx < total;
         idx += (size_t)gridDim.x * blockDim.x) {
        int h = (int)(idx & 2047);
        size_t row = idx >> 11;
        fin[idx] = (h < HID) ? ctx[row * HID + h] : y1[row * HID + (h - HID)];
    }
}

__global__ void copy_kernel(const float* __restrict__ src, float* __restrict__ dst, int n)
{
    int i = blockIdx.x * blockDim.x + threadIdx.x;
    if (i < n) dst[i] = src[i];
}

// ---------------------------------------------------------------------------
extern "C" void kernel_launch(void* const* d_in, const int* in_sizes, int n_in,
                              void* d_out, int out_size, void* d_ws, size_t ws_size,
                              hipStream_t stream)
{
    const float* enc   = (const float*)d_in[0];
    const float* ctxin = (const float*)d_in[1];
    const float* h0    = (const float*)d_in[2];
    const float* c0    = (const float*)d_in[3];
    const float* emb   = (const float*)d_in[4];
    const float* aw1   = (const float*)d_in[5];
    const float* ab1   = (const float*)d_in[6];
    const float* aw2   = (const float*)d_in[7];
    const float* ab2   = (const float*)d_in[8];
    const float* Wih0  = (const float*)d_in[9];
    const float* Whh0  = (const float*)d_in[10];
    const float* bih0  = (const float*)d_in[11];
    const float* bhh0  = (const float*)d_in[12];
    const float* Wih1  = (const float*)d_in[13];
    const float* Whh1  = (const float*)d_in[14];
    const float* bih1  = (const float*)d_in[15];
    const float* bhh1  = (const float*)d_in[16];
    const float* fc1w  = (const float*)d_in[17];
    const float* fc1b  = (const float*)d_in[18];
    const float* fc2w  = (const float*)d_in[19];
    const float* fc2b  = (const float*)d_in[20];
    const int*   tw    = (const int*)d_in[21];
    const int*   lens  = (const int*)d_in[22];

    float* ws = (float*)d_ws;
    float* buf_x       = ws;                         // 4,194,304  (x; later fc1out)
    float* buf_gates   = ws + 4194304;               // 8,388,608  (gates; later fin)
    float* buf_y0      = ws + 12582912;              // 2,097,152
    float* buf_y1      = ws + 14680064;              // 2,097,152
    float* buf_hA      = ws + 16777216;              // 32,768
    float* buf_hB      = ws + 16809984;              // 32,768
    float* buf_c       = ws + 16842752;              // 32,768
    float* buf_hidden1 = ws + 16875520;              // 1,048,576
    float* buf_p       = ws + 17924096;              // 2,048
    int*   buf_win     = (int*)(ws + 17926144);      // 2,048
    float* buf_sel     = ws + 17928192;              // 3,309,568
    float* buf_fin     = buf_gates;                  // alias (gates dead by then)
    float* buf_fc1out  = buf_x;                      // alias (x dead by then)

    float* out   = (float*)d_out;
    float* out_hn  = out + Y_SZ;
    float* out_cn  = out + Y_SZ + HN_SZ;
    float* out_ctx = out + CTX_OFF;

    const int HC = BATCH * HID;   // 32768

    // 1. x = [embedding[tw], context]
    embed_concat_kernel<<<4096, 256, 0, stream>>>(emb, ctxin, tw, buf_x);

    // 2. gates0_pre = x @ Wih0^T + bih0 + bhh0
    gemm_bt<<<dim3(4096 / 64, 2048 / 128), 256, 0, stream>>>(
        buf_x, Wih0, bih0, bhh0, buf_gates, 2048, 4096, 2048, 0);

    // 3. LSTM layer 0
    copy_kernel<<<128, 256, 0, stream>>>(h0, buf_hA, HC);
    copy_kernel<<<128, 256, 0, stream>>>(c0, buf_c, HC);
    for (int t = 0; t < T_STEPS; ++t) {
        const float* hin = (t & 1) ? buf_hB : buf_hA;
        float* hout      = (t & 1) ? buf_hA : buf_hB;
        lstm_step_kernel<<<256, 128, 0, stream>>>(
            buf_gates + (size_t)t * BATCH * 4096, Whh0, hin, buf_c, hout,
            buf_y0 + (size_t)t * HC);
    }
    copy_kernel<<<128, 256, 0, stream>>>(buf_hA, out_hn, HC);        // final h (t=63 wrote hA)
    copy_kernel<<<128, 256, 0, stream>>>(buf_c, out_cn, HC);

    // 4. gates1_pre = y0 @ Wih1^T + bih1 + bhh1
    gemm_bt<<<dim3(4096 / 64, 2048 / 128), 256, 0, stream>>>(
        buf_y0, Wih1, bih1, bhh1, buf_gates, 2048, 4096, 1024, 0);

    // 5. LSTM layer 1
    copy_kernel<<<128, 256, 0, stream>>>(h0 + HC, buf_hA, HC);
    copy_kernel<<<128, 256, 0, stream>>>(c0 + HC, buf_c, HC);
    for (int t = 0; t < T_STEPS; ++t) {
        const float* hin = (t & 1) ? buf_hB : buf_hA;
        float* hout      = (t & 1) ? buf_hA : buf_hB;
        lstm_step_kernel<<<256, 128, 0, stream>>>(
            buf_gates + (size_t)t * BATCH * 4096, Whh1, hin, buf_c, hout,
            buf_y1 + (size_t)t * HC);
    }
    copy_kernel<<<128, 256, 0, stream>>>(buf_hA, out_hn + HC, HC);
    copy_kernel<<<128, 256, 0, stream>>>(buf_c, out_cn + HC, HC);

    // 6. Attention
    gemm_bt<<<dim3(512 / 64, 2048 / 128), 256, 0, stream>>>(
        buf_y1, aw1, ab1, nullptr, buf_hidden1, 2048, 512, 1024, 2 /*tanh*/);
    attn_p_kernel<<<2048, 64, 0, stream>>>(buf_hidden1, aw2, ab2, lens, buf_p, buf_win);
    sel_gather_kernel<<<2048, 256, 0, stream>>>(enc, buf_win, buf_sel);
    attn_fused_kernel<<<2048, 128, 0, stream>>>(buf_y1, buf_sel, buf_p, buf_win, lens, out_ctx);

    // 7. fc1: relu(concat([ctx, y1]) @ fc1_w^T + fc1_b)
    concat_fin_kernel<<<4096, 256, 0, stream>>>(out_ctx, buf_y1, buf_fin);
    gemm_bt<<<dim3(1024 / 64, 2048 / 128), 256, 0, stream>>>(
        buf_fin, fc1w, fc1b, nullptr, buf_fc1out, 2048, 1024, 2048, 1 /*relu*/);

    // 8. fc2: y = fc1out @ fc2_w^T + fc2_b  -> d_out[0 .. T*B*V)
    gemm_bt<<<dim3(VOCAB / 64, 2048 / 128), 256, 0, stream>>>(
        buf_fc1out, fc2w, fc2b, nullptr, out, 2048, VOCAB, 1024, 0);
}